// Round 4
// baseline (390.518 us; speedup 1.0000x reference)
//
#include <hip/hip_runtime.h>
#include <hip/hip_bf16.h>
#include <stdint.h>

// Problem: out[b,i] = sum_j a_ext[b,j] * W[hash_idx[i,j]]
//   B=4096, FAN_IN=4096 (+1 bias col), FAN_OUT=4096, K-table=65536
// Strategy: materialize bf16 A_ext [B][KP] and Wv [FAN_OUT][KP] (K padded
// 4097->4160 with zeros), then m97-style bf16 MFMA GEMM-BT into fp32 C.
// R2: build_wv = LDS-resident two-phase gather (64KB half-table in LDS).
// R3: gemm BK=64 was NEUTRAL (barrier drain not binding) -> reverted to BK=32.
// R4: build_wv v2 — 8 rows/block (halves W-refill L2 traffic), results packed
//     to uint in registers, 4B-coalesced stores.

#define B_DIM   4096
#define FAN_IN  4096
#define FAN_OUT 4096
#define KD      (FAN_IN + 1)   // 4097
#define KP      4160           // padded to multiple of 64 (130 * BK)

#define BM 128
#define BN 128
#define BK 32

#define WVROWS 8               // rows per build_wv block

typedef __attribute__((ext_vector_type(8))) short  short8;   // 8 bf16 = 4 VGPRs
typedef __attribute__((ext_vector_type(4))) float  floatx4;  // MFMA acc

__device__ __forceinline__ unsigned short f2bf(float f) {
  union { float f; unsigned u; } v; v.f = f;
  unsigned u = v.u;
  u += 0x7fffu + ((u >> 16) & 1u);   // round-to-nearest-even
  return (unsigned short)(u >> 16);
}

__device__ __forceinline__ void async16(const void* g, void* l) {
  // direct global->LDS DMA, 16B/lane; LDS dest = wave-uniform base + lane*16
  __builtin_amdgcn_global_load_lds(
      (const __attribute__((address_space(1))) void*)g,
      (__attribute__((address_space(3))) void*)l, 16, 0, 0);
}

// ---- Kernel 1: A_ext[b][j] = bf16(a[b][j]); col 4096 = 1.0; cols 4097..KP-1 = 0
__global__ __launch_bounds__(256) void build_aext(
    const float* __restrict__ a, unsigned short* __restrict__ Ae) {
  const int row = blockIdx.x;
  const float* ar = a + (size_t)row * FAN_IN;
  unsigned short* er = Ae + (size_t)row * KP;
  for (int j4 = threadIdx.x; j4 < KP / 4; j4 += 256) {
    const int j = j4 * 4;
    float x0, x1, x2, x3;
    if (j + 3 < FAN_IN) {
      const float4 v = *(const float4*)(ar + j);   // 16B-aligned (row stride 16KB)
      x0 = v.x; x1 = v.y; x2 = v.z; x3 = v.w;
    } else {
      x0 = (j + 0 < FAN_IN) ? ar[j + 0] : ((j + 0 == FAN_IN) ? 1.0f : 0.0f);
      x1 = (j + 1 < FAN_IN) ? ar[j + 1] : ((j + 1 == FAN_IN) ? 1.0f : 0.0f);
      x2 = (j + 2 < FAN_IN) ? ar[j + 2] : ((j + 2 == FAN_IN) ? 1.0f : 0.0f);
      x3 = (j + 3 < FAN_IN) ? ar[j + 3] : ((j + 3 == FAN_IN) ? 1.0f : 0.0f);
    }
    ushort4 o;
    o.x = f2bf(x0); o.y = f2bf(x1); o.z = f2bf(x2); o.w = f2bf(x3);
    *(ushort4*)(er + j) = o;   // 8B store, aligned (row stride 8320B, j mult of 4)
  }
}

// ---- Kernel 2 (R4): Wv[i][j] = bf16(W[hash_idx[i][j]]) via LDS-resident table.
// 512 blocks x 512 threads; block handles 8 rows. Two phases: LDS holds
// bf16(W[h*32768 .. +32768)) (64 KB). Thread t owns element pairs
// j = 2*(i*512+t), 2*(i*512+t)+1 for i<4 (covers j=0..4095); bias col 4096 via
// LDS broadcast; pads 4097..4159 zeroed. Stores are packed 4B, fully coalesced.
__global__ __launch_bounds__(512) void build_wv(
    const int* __restrict__ hidx, const float* __restrict__ W,
    unsigned short* __restrict__ Wv) {
  __shared__ unsigned short wl[32768];   // 64 KB: half of W as bf16
  __shared__ unsigned short biasv[WVROWS];
  const int t  = threadIdx.x;
  const int r0 = blockIdx.x * WVROWS;

  // Index loads: lane t reads hr[2*j2] and hr[2*j2+1] (coalesced stride-8 pairs)
  int idx[WVROWS][8];
  unsigned int rp[WVROWS][4];
#pragma unroll
  for (int row = 0; row < WVROWS; row++) {
    const int* hr = hidx + (size_t)(r0 + row) * KD;
#pragma unroll
    for (int i = 0; i < 4; i++) {
      const int j2 = i * 512 + t;
      idx[row][2 * i]     = hr[2 * j2];
      idx[row][2 * i + 1] = hr[2 * j2 + 1];
      rp[row][i] = 0;
    }
  }
  int bidx = 0; unsigned short bval = 0;
  if (t < WVROWS) bidx = hidx[(size_t)(r0 + t) * KD + 4096];

  for (int h = 0; h < 2; h++) {
    __syncthreads();   // protect phase-0 reads before phase-1 refill
    // Fill LDS: 32768 floats -> bf16 (float4 loads, 8B LDS writes; W is L2-hot)
    const float4* Wb = (const float4*)(W + h * 32768);
#pragma unroll
    for (int i = 0; i < 16; i++) {
      const int f4 = i * 512 + t;
      const float4 v = Wb[f4];
      ushort4 o;
      o.x = f2bf(v.x); o.y = f2bf(v.y); o.z = f2bf(v.z); o.w = f2bf(v.w);
      *(ushort4*)&wl[f4 * 4] = o;
    }
    __syncthreads();
    const int lo = h << 15;
#pragma unroll
    for (int row = 0; row < WVROWS; row++)
#pragma unroll
      for (int i = 0; i < 4; i++) {
#pragma unroll
        for (int half = 0; half < 2; half++) {
          const int v = idx[row][2 * i + half];
          if ((v & 32768) == lo) {
            const unsigned int g = wl[v & 32767];   // random ds_read_u16
            rp[row][i] = half ? ((rp[row][i] & 0x0000FFFFu) | (g << 16))
                              : ((rp[row][i] & 0xFFFF0000u) | g);
          }
        }
      }
    if (t < WVROWS && (bidx & 32768) == lo) bval = wl[bidx & 32767];
  }
  if (t < WVROWS) biasv[t] = bval;
  __syncthreads();

  // Coalesced 4B stores + bias/pad tail (shorts 4096..4159 = uints 2048..2079)
#pragma unroll
  for (int row = 0; row < WVROWS; row++) {
    unsigned int* wr32 = (unsigned int*)(Wv + (size_t)(r0 + row) * KP);
#pragma unroll
    for (int i = 0; i < 4; i++)
      wr32[i * 512 + t] = rp[row][i];
    if (t < 32) wr32[2048 + t] = (t == 0) ? (unsigned int)biasv[row] : 0u;
  }
}

// ---- Kernel 3 (R2 config): C[M][N] = A[M][KP] * Bm[N][KP]^T  (bf16 in, fp32 out)
// 128x128 block tile, BK=32, 4 waves in 2x2, each wave 64x64 = 4x4 MFMA tiles.
__global__ __launch_bounds__(256) void gemm_bt(
    const unsigned short* __restrict__ A, const unsigned short* __restrict__ Bm,
    float* __restrict__ C, int M, int N) {
  __shared__ __align__(16) unsigned short As[BM * BK];   // 8 KB, row-major [128][32]
  __shared__ __align__(16) unsigned short Bs[BN * BK];   // 8 KB

  const int tid  = threadIdx.x;
  const int lane = tid & 63;
  const int wave = tid >> 6;
  const int bm = blockIdx.y * BM;
  const int bn = blockIdx.x * BN;
  const int wm = (wave >> 1) * 64;
  const int wn = (wave & 1) * 64;
  const int q  = lane >> 4;        // k-quad for MFMA operand layout
  const int r  = lane & 15;        // m/n index within 16
  const int srow = lane >> 2;      // staging: 16 rows per wave-load
  const int scol = (lane & 3) * 8; // staging: 8 bf16 (16B) per lane

  floatx4 acc[4][4] = {};

  for (int k0 = 0; k0 < KP; k0 += BK) {
    // stage: each wave DMAs 2x16 rows of A and of B (64B/row = 4 lanes/row)
#pragma unroll
    for (int l = 0; l < 2; l++) {
      const int trow = wave * 32 + l * 16;
      async16(A  + (size_t)(bm + trow + srow) * KP + k0 + scol, &As[trow * BK]);
      async16(Bm + (size_t)(bn + trow + srow) * KP + k0 + scol, &Bs[trow * BK]);
    }
    __syncthreads();   // emits s_waitcnt vmcnt(0) -> DMA complete for all waves

    short8 af[4], bf[4];
#pragma unroll
    for (int t = 0; t < 4; t++) {
      // A-operand layout: A[m = lane&15][k = q*8 + j] (16B contig -> ds_read_b128)
      af[t] = *(const short8*)&As[(wm + t * 16 + r) * BK + q * 8];
      bf[t] = *(const short8*)&Bs[(wn + t * 16 + r) * BK + q * 8];
    }
#pragma unroll
    for (int mt = 0; mt < 4; mt++)
#pragma unroll
      for (int nt = 0; nt < 4; nt++)
        acc[mt][nt] = __builtin_amdgcn_mfma_f32_16x16x32_bf16(
            af[mt], bf[nt], acc[mt][nt], 0, 0, 0);
    __syncthreads();   // protect LDS from next iteration's staging
  }

  // C/D layout (verified m89/m91): col = lane&15, row = q*4 + reg
#pragma unroll
  for (int mt = 0; mt < 4; mt++)
#pragma unroll
    for (int nt = 0; nt < 4; nt++) {
      const int row0 = bm + wm + mt * 16 + q * 4;
      const int col  = bn + wn + nt * 16 + r;
#pragma unroll
      for (int i = 0; i < 4; i++)
        C[(size_t)(row0 + i) * N + col] = acc[mt][nt][i];
    }
}

extern "C" void kernel_launch(void* const* d_in, const int* in_sizes, int n_in,
                              void* d_out, int out_size, void* d_ws, size_t ws_size,
                              hipStream_t stream) {
  const float* a    = (const float*)d_in[0];   // [4096, 4096] fp32
  const int*   hidx = (const int*)d_in[1];     // [4096, 4097] int32
  const float* W    = (const float*)d_in[2];   // [65536] fp32
  float*       out  = (float*)d_out;           // [4096, 4096] fp32

  // workspace layout: A_ext bf16 [B_DIM][KP] | Wv bf16 [FAN_OUT][KP]  (68.2 MB)
  unsigned short* Ae = (unsigned short*)d_ws;
  unsigned short* Wv = Ae + (size_t)B_DIM * KP;

  build_aext<<<B_DIM, 256, 0, stream>>>(a, Ae);
  build_wv<<<FAN_OUT / WVROWS, 512, 0, stream>>>(hidx, W, Wv);
  gemm_bt<<<dim3(FAN_OUT / BN, B_DIM / BM), 256, 0, stream>>>(Ae, Wv, out, B_DIM, FAN_OUT);
}

// Round 5
// 347.464 us; speedup vs baseline: 1.1239x; 1.1239x over previous
//
#include <hip/hip_runtime.h>
#include <hip/hip_bf16.h>
#include <stdint.h>

// Problem: out[b,i] = sum_j a_ext[b,j] * W[hash_idx[i,j]]
//   B=4096, FAN_IN=4096 (+1 bias col), FAN_OUT=4096, K-table=65536
// Strategy: materialize bf16 A_ext [B][KP] and Wv [FAN_OUT][KP] (K padded
// 4097->4160 with zeros), then m97-style bf16 MFMA GEMM-BT into fp32 C.
// R2: build_wv = LDS-resident two-phase gather (64KB half-table in LDS).
// R3: gemm BK=64 NEUTRAL (barrier drain not binding) -> BK=32.
// R4: build_wv 8-rows/block REGRESSED (reg pressure) -> reverted to R2 form.
// R5: gemm __launch_bounds__(256,4) to force 4 blocks/CU (kills the 256-block
//     tail at 3/CU, 16 waves/CU latency hiding); staging ptrs hoisted out of
//     the K-loop (ptr += BK) to cut per-iter address VALU.

#define B_DIM   4096
#define FAN_IN  4096
#define FAN_OUT 4096
#define KD      (FAN_IN + 1)   // 4097
#define KP      4160           // padded to multiple of 64 (130 * BK)

#define BM 128
#define BN 128
#define BK 32

typedef __attribute__((ext_vector_type(8))) short  short8;   // 8 bf16 = 4 VGPRs
typedef __attribute__((ext_vector_type(4))) float  floatx4;  // MFMA acc

__device__ __forceinline__ unsigned short f2bf(float f) {
  union { float f; unsigned u; } v; v.f = f;
  unsigned u = v.u;
  u += 0x7fffu + ((u >> 16) & 1u);   // round-to-nearest-even
  return (unsigned short)(u >> 16);
}

__device__ __forceinline__ void async16(const void* g, void* l) {
  // direct global->LDS DMA, 16B/lane; LDS dest = wave-uniform base + lane*16
  __builtin_amdgcn_global_load_lds(
      (const __attribute__((address_space(1))) void*)g,
      (__attribute__((address_space(3))) void*)l, 16, 0, 0);
}

// ---- Kernel 1: A_ext[b][j] = bf16(a[b][j]); col 4096 = 1.0; cols 4097..KP-1 = 0
__global__ __launch_bounds__(256) void build_aext(
    const float* __restrict__ a, unsigned short* __restrict__ Ae) {
  const int row = blockIdx.x;
  const float* ar = a + (size_t)row * FAN_IN;
  unsigned short* er = Ae + (size_t)row * KP;
  for (int j4 = threadIdx.x; j4 < KP / 4; j4 += 256) {
    const int j = j4 * 4;
    float x0, x1, x2, x3;
    if (j + 3 < FAN_IN) {
      const float4 v = *(const float4*)(ar + j);   // 16B-aligned (row stride 16KB)
      x0 = v.x; x1 = v.y; x2 = v.z; x3 = v.w;
    } else {
      x0 = (j + 0 < FAN_IN) ? ar[j + 0] : ((j + 0 == FAN_IN) ? 1.0f : 0.0f);
      x1 = (j + 1 < FAN_IN) ? ar[j + 1] : ((j + 1 == FAN_IN) ? 1.0f : 0.0f);
      x2 = (j + 2 < FAN_IN) ? ar[j + 2] : ((j + 2 == FAN_IN) ? 1.0f : 0.0f);
      x3 = (j + 3 < FAN_IN) ? ar[j + 3] : ((j + 3 == FAN_IN) ? 1.0f : 0.0f);
    }
    ushort4 o;
    o.x = f2bf(x0); o.y = f2bf(x1); o.z = f2bf(x2); o.w = f2bf(x3);
    *(ushort4*)(er + j) = o;   // 8B store, aligned (row stride 8320B, j mult of 4)
  }
}

// ---- Kernel 2 (R2 version, measured-best): Wv[i][j] = bf16(W[hash_idx[i][j]]).
// 1024 blocks x 512 threads; block handles 4 rows. Two phases: LDS holds
// bf16(W[h*32768 .. h*32768+32768)) (64 KB); indices live in registers.
__global__ __launch_bounds__(512) void build_wv(
    const int* __restrict__ hidx, const float* __restrict__ W,
    unsigned short* __restrict__ Wv) {
  __shared__ unsigned short wl[32768];   // 64 KB: half of W as bf16
  const int t  = threadIdx.x;
  const int r0 = blockIdx.x * 4;

  // Load this block's indices into registers (fully coalesced: 4B/lane-consecutive)
  int          idx[4][9];
  unsigned short res[4][9];
#pragma unroll
  for (int row = 0; row < 4; row++) {
    const int* hr = hidx + (size_t)(r0 + row) * KD;
#pragma unroll
    for (int i = 0; i < 9; i++) {
      const int j = i * 512 + t;
      idx[row][i] = (j < KD) ? hr[j] : 0;
      res[row][i] = 0;
    }
  }

  for (int h = 0; h < 2; h++) {
    __syncthreads();   // protect phase-0 reads before phase-1 refill
    // Fill LDS: 32768 floats -> bf16. float4 loads, ushort4 (8B) LDS writes
    // (lane byte-stride 8 -> 2-way bank alias, free per m136).
    const float4* Wb = (const float4*)(W + h * 32768);
#pragma unroll
    for (int i = 0; i < 16; i++) {
      const int f4 = i * 512 + t;
      const float4 v = Wb[f4];
      ushort4 o;
      o.x = f2bf(v.x); o.y = f2bf(v.y); o.z = f2bf(v.z); o.w = f2bf(v.w);
      *(ushort4*)&wl[f4 * 4] = o;
    }
    __syncthreads();
    const int lo = h << 15;
#pragma unroll
    for (int row = 0; row < 4; row++)
#pragma unroll
      for (int i = 0; i < 9; i++) {
        const int v = idx[row][i];
        if ((v & 32768) == lo)            // index falls in resident half
          res[row][i] = wl[v & 32767];    // random ds_read_u16
      }
  }

  // Store results + zero the KD..KP-1 pad columns
#pragma unroll
  for (int row = 0; row < 4; row++) {
    unsigned short* wr = Wv + (size_t)(r0 + row) * KP;
#pragma unroll
    for (int i = 0; i < 9; i++) {
      const int j = i * 512 + t;
      if (j < KD) wr[j] = res[row][i];
    }
    if (t < KP - KD) wr[KD + t] = 0;
  }
}

// ---- Kernel 3 (R5): C[M][N] = A[M][KP] * Bm[N][KP]^T  (bf16 in, fp32 out)
// 128x128 block tile, BK=32, 4 waves in 2x2, each wave 64x64 = 4x4 MFMA tiles.
// __launch_bounds__(256,4): cap 128 unified regs/wave -> 4 blocks/CU resident.
__global__ __launch_bounds__(256, 4) void gemm_bt(
    const unsigned short* __restrict__ A, const unsigned short* __restrict__ Bm,
    float* __restrict__ C, int M, int N) {
  __shared__ __align__(16) unsigned short As[BM * BK];   // 8 KB, row-major [128][32]
  __shared__ __align__(16) unsigned short Bs[BN * BK];   // 8 KB

  const int tid  = threadIdx.x;
  const int lane = tid & 63;
  const int wave = tid >> 6;
  const int bm = blockIdx.y * BM;
  const int bn = blockIdx.x * BN;
  const int wm = (wave >> 1) * 64;
  const int wn = (wave & 1) * 64;
  const int q  = lane >> 4;        // k-quad for MFMA operand layout
  const int r  = lane & 15;        // m/n index within 16
  const int srow = lane >> 2;      // staging: 16 rows per wave-load
  const int scol = (lane & 3) * 8; // staging: 8 bf16 (16B) per lane

  // Hoisted staging pointers: advance by BK each K-iter (2 VALU adds per ptr).
  const int trow = wave * 32;
  const unsigned short* pa0 = A  + (size_t)(bm + trow      + srow) * KP + scol;
  const unsigned short* pa1 = A  + (size_t)(bm + trow + 16 + srow) * KP + scol;
  const unsigned short* pb0 = Bm + (size_t)(bn + trow      + srow) * KP + scol;
  const unsigned short* pb1 = Bm + (size_t)(bn + trow + 16 + srow) * KP + scol;
  unsigned short* lA0 = &As[(trow     ) * BK];
  unsigned short* lA1 = &As[(trow + 16) * BK];
  unsigned short* lB0 = &Bs[(trow     ) * BK];
  unsigned short* lB1 = &Bs[(trow + 16) * BK];

  floatx4 acc[4][4] = {};

  for (int k0 = 0; k0 < KP; k0 += BK) {
    async16(pa0, lA0);  async16(pa1, lA1);
    async16(pb0, lB0);  async16(pb1, lB1);
    pa0 += BK; pa1 += BK; pb0 += BK; pb1 += BK;
    __syncthreads();   // emits s_waitcnt vmcnt(0) -> DMA complete for all waves

    short8 af[4], bf[4];
#pragma unroll
    for (int t = 0; t < 4; t++) {
      // A-operand layout: A[m = lane&15][k = q*8 + j] (16B contig -> ds_read_b128)
      af[t] = *(const short8*)&As[(wm + t * 16 + r) * BK + q * 8];
      bf[t] = *(const short8*)&Bs[(wn + t * 16 + r) * BK + q * 8];
    }
#pragma unroll
    for (int mt = 0; mt < 4; mt++)
#pragma unroll
      for (int nt = 0; nt < 4; nt++)
        acc[mt][nt] = __builtin_amdgcn_mfma_f32_16x16x32_bf16(
            af[mt], bf[nt], acc[mt][nt], 0, 0, 0);
    __syncthreads();   // protect LDS from next iteration's staging
  }

  // C/D layout (verified m89/m91): col = lane&15, row = q*4 + reg
#pragma unroll
  for (int mt = 0; mt < 4; mt++)
#pragma unroll
    for (int nt = 0; nt < 4; nt++) {
      const int row0 = bm + wm + mt * 16 + q * 4;
      const int col  = bn + wn + nt * 16 + r;
#pragma unroll
      for (int i = 0; i < 4; i++)
        C[(size_t)(row0 + i) * N + col] = acc[mt][nt][i];
    }
}

extern "C" void kernel_launch(void* const* d_in, const int* in_sizes, int n_in,
                              void* d_out, int out_size, void* d_ws, size_t ws_size,
                              hipStream_t stream) {
  const float* a    = (const float*)d_in[0];   // [4096, 4096] fp32
  const int*   hidx = (const int*)d_in[1];     // [4096, 4097] int32
  const float* W    = (const float*)d_in[2];   // [65536] fp32
  float*       out  = (float*)d_out;           // [4096, 4096] fp32

  // workspace layout: A_ext bf16 [B_DIM][KP] | Wv bf16 [FAN_OUT][KP]  (68.2 MB)
  unsigned short* Ae = (unsigned short*)d_ws;
  unsigned short* Wv = Ae + (size_t)B_DIM * KP;

  build_aext<<<B_DIM, 256, 0, stream>>>(a, Ae);
  build_wv<<<FAN_OUT / 4, 512, 0, stream>>>(hidx, W, Wv);
  gemm_bt<<<dim3(FAN_OUT / BN, B_DIM / BM), 256, 0, stream>>>(Ae, Wv, out, B_DIM, FAN_OUT);
}

// Round 7
// 339.517 us; speedup vs baseline: 1.1502x; 1.0234x over previous
//
#include <hip/hip_runtime.h>
#include <hip/hip_bf16.h>
#include <stdint.h>

// Problem: out[b,i] = sum_j a_ext[b,j] * W[hash_idx[i,j]]
//   B=4096, FAN_IN=4096 (+1 bias col), FAN_OUT=4096, K-table=65536
// Strategy: materialize bf16 A_ext [B][KP] and Wv [FAN_OUT][KP] (K padded
// 4097->4160 with zeros), then bf16 MFMA GEMM-BT into fp32 C.
// R2: build_wv = LDS-resident two-phase gather (64KB half-table in LDS).
// R3: gemm BK=64 NEUTRAL -> BK=32.  R4: wv 8-rows/block REGRESSED -> R2 form.
// R5: WIN: launch_bounds(256,4) + hoisted ptrs: gemm 216->182us, VALU 31->12%.
// R6: FAILED post-timing correctness (replay-only divergence). Fusion+stagger
//     reverted. Diagnosis: 2-barrier structure's LDS WAR safety depends on the
//     compiler not moving global_load_lds across s_barrier — fragile.
// R7: gemm = single-barrier LDS DOUBLE-BUFFER: tile m+1 is issued after
//     barrier(m) into the buffer whose readers finished at compute(m-1);
//     drained by barrier(m+1)'s per-wave vmcnt(0). Race-proof by structure,
//     halves barriers, real load/compute overlap. Prep = R5 exact.

#define B_DIM   4096
#define FAN_IN  4096
#define FAN_OUT 4096
#define KD      (FAN_IN + 1)   // 4097
#define KP      4160           // padded to multiple of 64 (130 * BK)

#define BM 128
#define BN 128
#define BK 32

typedef __attribute__((ext_vector_type(8))) short  short8;   // 8 bf16 = 4 VGPRs
typedef __attribute__((ext_vector_type(4))) float  floatx4;  // MFMA acc

__device__ __forceinline__ unsigned short f2bf(float f) {
  union { float f; unsigned u; } v; v.f = f;
  unsigned u = v.u;
  u += 0x7fffu + ((u >> 16) & 1u);   // round-to-nearest-even
  return (unsigned short)(u >> 16);
}

__device__ __forceinline__ void async16(const void* g, void* l) {
  // direct global->LDS DMA, 16B/lane; LDS dest = wave-uniform base + lane*16
  __builtin_amdgcn_global_load_lds(
      (const __attribute__((address_space(1))) void*)g,
      (__attribute__((address_space(3))) void*)l, 16, 0, 0);
}

// ---- Kernel 1: A_ext[b][j] = bf16(a[b][j]); col 4096 = 1.0; cols 4097..KP-1 = 0
__global__ __launch_bounds__(256) void build_aext(
    const float* __restrict__ a, unsigned short* __restrict__ Ae) {
  const int row = blockIdx.x;
  const float* ar = a + (size_t)row * FAN_IN;
  unsigned short* er = Ae + (size_t)row * KP;
  for (int j4 = threadIdx.x; j4 < KP / 4; j4 += 256) {
    const int j = j4 * 4;
    float x0, x1, x2, x3;
    if (j + 3 < FAN_IN) {
      const float4 v = *(const float4*)(ar + j);   // 16B-aligned (row stride 16KB)
      x0 = v.x; x1 = v.y; x2 = v.z; x3 = v.w;
    } else {
      x0 = (j + 0 < FAN_IN) ? ar[j + 0] : ((j + 0 == FAN_IN) ? 1.0f : 0.0f);
      x1 = (j + 1 < FAN_IN) ? ar[j + 1] : ((j + 1 == FAN_IN) ? 1.0f : 0.0f);
      x2 = (j + 2 < FAN_IN) ? ar[j + 2] : ((j + 2 == FAN_IN) ? 1.0f : 0.0f);
      x3 = (j + 3 < FAN_IN) ? ar[j + 3] : ((j + 3 == FAN_IN) ? 1.0f : 0.0f);
    }
    ushort4 o;
    o.x = f2bf(x0); o.y = f2bf(x1); o.z = f2bf(x2); o.w = f2bf(x3);
    *(ushort4*)(er + j) = o;   // 8B store, aligned (row stride 8320B, j mult of 4)
  }
}

// ---- Kernel 2 (R2 version, measured-best): Wv[i][j] = bf16(W[hash_idx[i][j]]).
// 1024 blocks x 512 threads; block handles 4 rows. Two phases: LDS holds
// bf16(W[h*32768 .. h*32768+32768)) (64 KB); indices live in registers.
__global__ __launch_bounds__(512) void build_wv(
    const int* __restrict__ hidx, const float* __restrict__ W,
    unsigned short* __restrict__ Wv) {
  __shared__ unsigned short wl[32768];   // 64 KB: half of W as bf16
  const int t  = threadIdx.x;
  const int r0 = blockIdx.x * 4;

  // Load this block's indices into registers (fully coalesced: 4B/lane-consecutive)
  int          idx[4][9];
  unsigned short res[4][9];
#pragma unroll
  for (int row = 0; row < 4; row++) {
    const int* hr = hidx + (size_t)(r0 + row) * KD;
#pragma unroll
    for (int i = 0; i < 9; i++) {
      const int j = i * 512 + t;
      idx[row][i] = (j < KD) ? hr[j] : 0;
      res[row][i] = 0;
    }
  }

  for (int h = 0; h < 2; h++) {
    __syncthreads();   // protect phase-0 reads before phase-1 refill
    // Fill LDS: 32768 floats -> bf16. float4 loads, ushort4 (8B) LDS writes
    // (lane byte-stride 8 -> 2-way bank alias, free per m136).
    const float4* Wb = (const float4*)(W + h * 32768);
#pragma unroll
    for (int i = 0; i < 16; i++) {
      const int f4 = i * 512 + t;
      const float4 v = Wb[f4];
      ushort4 o;
      o.x = f2bf(v.x); o.y = f2bf(v.y); o.z = f2bf(v.z); o.w = f2bf(v.w);
      *(ushort4*)&wl[f4 * 4] = o;
    }
    __syncthreads();
    const int lo = h << 15;
#pragma unroll
    for (int row = 0; row < 4; row++)
#pragma unroll
      for (int i = 0; i < 9; i++) {
        const int v = idx[row][i];
        if ((v & 32768) == lo)            // index falls in resident half
          res[row][i] = wl[v & 32767];    // random ds_read_u16
      }
  }

  // Store results + zero the KD..KP-1 pad columns
#pragma unroll
  for (int row = 0; row < 4; row++) {
    unsigned short* wr = Wv + (size_t)(r0 + row) * KP;
#pragma unroll
    for (int i = 0; i < 9; i++) {
      const int j = i * 512 + t;
      if (j < KD) wr[j] = res[row][i];
    }
    if (t < KP - KD) wr[KD + t] = 0;
  }
}

// ---- Kernel 3 (R7): C[M][N] = A[M][KP] * Bm[N][KP]^T  (bf16 in, fp32 out)
// 128x128 tile, BK=32, 4 waves 2x2, 4x4 MFMA accs/wave. Single-barrier LDS
// double-buffer:
//   iter m: __syncthreads()  [drains my tile-m loads; all waves done reading
//                             buf (m+1)&1 at compute(m-1)]
//           issue tile m+1 -> buf (m+1)&1   (in flight during compute)
//           compute from buf m&1
// WAR/RAW safe independent of compiler scheduling around the barrier.
__global__ __launch_bounds__(256, 4) void gemm_bt(
    const unsigned short* __restrict__ A, const unsigned short* __restrict__ Bm,
    float* __restrict__ C, int M, int N) {
  __shared__ __align__(16) unsigned short As[2][BM * BK];   // 2 x 8 KB
  __shared__ __align__(16) unsigned short Bs[2][BN * BK];   // 2 x 8 KB

  const int tid  = threadIdx.x;
  const int lane = tid & 63;
  const int wave = tid >> 6;
  const int bm = blockIdx.y * BM;
  const int bn = blockIdx.x * BN;
  const int wm = (wave >> 1) * 64;
  const int wn = (wave & 1) * 64;
  const int q  = lane >> 4;        // k-quad for MFMA operand layout
  const int r  = lane & 15;        // m/n index within 16
  const int srow = lane >> 2;      // staging: 16 rows per wave-load
  const int scol = (lane & 3) * 8; // staging: 8 bf16 (16B) per lane

  // Hoisted staging pointers: advance by BK each K-iter.
  const int trow = wave * 32;
  const unsigned short* pa0 = A  + (size_t)(bm + trow      + srow) * KP + scol;
  const unsigned short* pa1 = A  + (size_t)(bm + trow + 16 + srow) * KP + scol;
  const unsigned short* pb0 = Bm + (size_t)(bn + trow      + srow) * KP + scol;
  const unsigned short* pb1 = Bm + (size_t)(bn + trow + 16 + srow) * KP + scol;
  const int l0 = trow * BK;        // LDS element offsets (wave-uniform)
  const int l1 = (trow + 16) * BK;

  // Preload tile 0 into buffer 0
  async16(pa0, &As[0][l0]);  async16(pa1, &As[0][l1]);
  async16(pb0, &Bs[0][l0]);  async16(pb1, &Bs[0][l1]);
  pa0 += BK; pa1 += BK; pb0 += BK; pb1 += BK;

  floatx4 acc[4][4] = {};
  int p = 0;
#pragma unroll 2
  for (int k0 = 0; k0 < KP; k0 += BK) {
    __syncthreads();   // per-wave vmcnt(0) drain + barrier: buf[p] tile ready,
                       // buf[p^1] readers (compute of iter m-1) all finished
    if (k0 + BK < KP) {
      async16(pa0, &As[p ^ 1][l0]);  async16(pa1, &As[p ^ 1][l1]);
      async16(pb0, &Bs[p ^ 1][l0]);  async16(pb1, &Bs[p ^ 1][l1]);
      pa0 += BK; pa1 += BK; pb0 += BK; pb1 += BK;
    }

    short8 af[4], bf[4];
#pragma unroll
    for (int t = 0; t < 4; t++) {
      // A-operand layout: A[m = lane&15][k = q*8 + j] (16B contig -> ds_read_b128)
      af[t] = *(const short8*)&As[p][(wm + t * 16 + r) * BK + q * 8];
      bf[t] = *(const short8*)&Bs[p][(wn + t * 16 + r) * BK + q * 8];
    }
#pragma unroll
    for (int mt = 0; mt < 4; mt++)
#pragma unroll
      for (int nt = 0; nt < 4; nt++)
        acc[mt][nt] = __builtin_amdgcn_mfma_f32_16x16x32_bf16(
            af[mt], bf[nt], acc[mt][nt], 0, 0, 0);
    p ^= 1;
  }

  // C/D layout (verified m89/m91): col = lane&15, row = q*4 + reg
#pragma unroll
  for (int mt = 0; mt < 4; mt++)
#pragma unroll
    for (int nt = 0; nt < 4; nt++) {
      const int row0 = bm + wm + mt * 16 + q * 4;
      const int col  = bn + wn + nt * 16 + r;
#pragma unroll
      for (int i = 0; i < 4; i++)
        C[(size_t)(row0 + i) * N + col] = acc[mt][nt][i];
    }
}

extern "C" void kernel_launch(void* const* d_in, const int* in_sizes, int n_in,
                              void* d_out, int out_size, void* d_ws, size_t ws_size,
                              hipStream_t stream) {
  const float* a    = (const float*)d_in[0];   // [4096, 4096] fp32
  const int*   hidx = (const int*)d_in[1];     // [4096, 4097] int32
  const float* W    = (const float*)d_in[2];   // [65536] fp32
  float*       out  = (float*)d_out;           // [4096, 4096] fp32

  // workspace layout: A_ext bf16 [B_DIM][KP] | Wv bf16 [FAN_OUT][KP]  (68.2 MB)
  unsigned short* Ae = (unsigned short*)d_ws;
  unsigned short* Wv = Ae + (size_t)B_DIM * KP;

  build_aext<<<B_DIM, 256, 0, stream>>>(a, Ae);
  build_wv<<<FAN_OUT / 4, 512, 0, stream>>>(hidx, W, Wv);
  gemm_bt<<<dim3(FAN_OUT / BN, B_DIM / BM), 256, 0, stream>>>(Ae, Wv, out, B_DIM, FAN_OUT);
}